// Round 16
// baseline (1468.673 us; speedup 1.0000x reference)
//
#include <hip/hip_runtime.h>
#include <math.h>

#define NN 8000
#define KK 32
#define HH 256
#define DE 128
#define NODES 4
#define THREADS 512
#define BIGLD 536
#define LDS_BYTES (128 * BIGLD * 2)

typedef __attribute__((ext_vector_type(8))) short bs8;
typedef __attribute__((ext_vector_type(4))) short bs4;
typedef __attribute__((ext_vector_type(4))) float f4;

#define LGK_FENCE() do { asm volatile("s_waitcnt lgkmcnt(0)" ::: "memory"); __builtin_amdgcn_sched_barrier(0); } while (0)

struct P {
  const float *nf, *ef, *ear, *ang;
  const float *ln1e_g, *ln1e_b;
  const float *b_ea, *b_nh, *b_eh, *b_gate, *b_cand;
  const float *ascal, *b_in, *b_out, *aw;
  const float *ln2n_g, *ln2n_b, *ln2e_g, *ln2e_b;
  const float *bn1, *bn2, *be1, *be2;
  const int *nbrl, *nbrc;
  const unsigned short *nhb;
  const unsigned short *wtEA, *wtNH, *wtEH, *wtG, *wtC, *wtIN, *wtOUT, *wtN1, *wtN2, *wtE1, *wtE2;
  float *on, *oe;
};

__device__ __forceinline__ unsigned short f2b(float f) {
  unsigned int u = __float_as_uint(f);
  unsigned int r = (u + 0x7fffu + ((u >> 16) & 1u)) >> 16;
  return (unsigned short)r;
}
__device__ __forceinline__ float b2f(unsigned short u) {
  return __uint_as_float(((unsigned int)u) << 16);
}
__device__ __forceinline__ unsigned int cvt_pk_bf16(float lo, float hi) {
  unsigned int r;
  asm("v_cvt_pk_bf16_f32 %0, %1, %2" : "=v"(r) : "v"(lo), "v"(hi));
  return r;
}
__device__ __forceinline__ bs4 pack4(float a, float b, float c, float d) {
  union { unsigned int u[2]; bs4 v; } x;
  x.u[0] = cvt_pk_bf16(a, b);
  x.u[1] = cvt_pk_bf16(c, d);
  return x.v;
}
__device__ __forceinline__ float fast_tanh(float x) {
  x = fminf(fmaxf(x, -12.f), 12.f);
  float e = __expf(2.f * x);
  return (e - 1.f) / (e + 1.f);
}
__device__ __forceinline__ float gelu_f(float x) {
  return 0.5f * x * (1.f + fast_tanh(0.7978845608f * (x + 0.044715f * x * x * x)));
}
__device__ __forceinline__ float sigmoid_f(float x) {
  return 1.f / (1.f + __expf(-x));
}

// acc[rt][ct] = mfma(Wfrag, Afrag): out row (A-row) = rt*16+(l&15),
// out col = cs + ct*16 + (l>>4)*4 + r. A in LDS stride BIGLD. W [outcol][KW].
template<int RT, int NCT, int KB, int KW>
__device__ __forceinline__ void gemmB(f4 acc[RT][NCT],
    const unsigned short* __restrict__ wt,
    const unsigned short* __restrict__ A, int cs, int l)
{
  const int lm = l & 15;
  const int lg = (l >> 4) << 3;
  #pragma unroll
  for (int kb = 0; kb < KB; ++kb) {
    bs8 wfr[NCT];
    #pragma unroll
    for (int ct = 0; ct < NCT; ++ct)
      wfr[ct] = *(const bs8*)(wt + (size_t)(cs + ct * 16 + lm) * KW + kb * 32 + lg);
    bs8 afr[RT];
    #pragma unroll
    for (int rt = 0; rt < RT; ++rt)
      afr[rt] = *(const bs8*)(A + (rt * 16 + lm) * BIGLD + kb * 32 + lg);
    #pragma unroll
    for (int rt = 0; rt < RT; ++rt)
      #pragma unroll
      for (int ct = 0; ct < NCT; ++ct)
        acc[rt][ct] = __builtin_amdgcn_mfma_f32_16x16x32_bf16(wfr[ct], afr[rt], acc[rt][ct], 0, 0, 0);
  }
}

// Dual-accumulator variant: two weight streams share one A-fragment load.
template<int RT, int NCT, int KB, int KW>
__device__ __forceinline__ void gemmB2(f4 acc0[RT][NCT], f4 acc1[RT][NCT],
    const unsigned short* __restrict__ wt0,
    const unsigned short* __restrict__ wt1,
    const unsigned short* __restrict__ A, int cs, int l)
{
  const int lm = l & 15;
  const int lg = (l >> 4) << 3;
  #pragma unroll
  for (int kb = 0; kb < KB; ++kb) {
    bs8 wfr0[NCT], wfr1[NCT];
    #pragma unroll
    for (int ct = 0; ct < NCT; ++ct) {
      wfr0[ct] = *(const bs8*)(wt0 + (size_t)(cs + ct * 16 + lm) * KW + kb * 32 + lg);
      wfr1[ct] = *(const bs8*)(wt1 + (size_t)(cs + ct * 16 + lm) * KW + kb * 32 + lg);
    }
    bs8 afr[RT];
    #pragma unroll
    for (int rt = 0; rt < RT; ++rt)
      afr[rt] = *(const bs8*)(A + (rt * 16 + lm) * BIGLD + kb * 32 + lg);
    #pragma unroll
    for (int rt = 0; rt < RT; ++rt)
      #pragma unroll
      for (int ct = 0; ct < NCT; ++ct) {
        acc0[rt][ct] = __builtin_amdgcn_mfma_f32_16x16x32_bf16(wfr0[ct], afr[rt], acc0[rt][ct], 0, 0, 0);
        acc1[rt][ct] = __builtin_amdgcn_mfma_f32_16x16x32_bf16(wfr1[ct], afr[rt], acc1[rt][ct], 0, 0, 0);
      }
  }
}

template<int RT, int NCT>
__device__ __forceinline__ void zero_acc(f4 acc[RT][NCT]) {
  #pragma unroll
  for (int rt = 0; rt < RT; ++rt)
    #pragma unroll
    for (int ct = 0; ct < NCT; ++ct) {
      acc[rt][ct][0] = 0.f; acc[rt][ct][1] = 0.f; acc[rt][ct][2] = 0.f; acc[rt][ct][3] = 0.f;
    }
}

template<int RT, int NCT, int ACTF>
__device__ __forceinline__ void storeB(unsigned short* dst,
    f4 acc[RT][NCT], const float* __restrict__ bias, int cs, int l)
{
  const int lm = l & 15;
  const int lr = (l >> 4) << 2;
  #pragma unroll
  for (int ct = 0; ct < NCT; ++ct) {
    f4 bv = *(const f4*)(bias + cs + ct * 16 + lr);
    #pragma unroll
    for (int rt = 0; rt < RT; ++rt) {
      float v[4];
      #pragma unroll
      for (int r = 0; r < 4; ++r) {
        v[r] = acc[rt][ct][r] + bv[r];
        if (ACTF == 1) v[r] = gelu_f(v[r]);
      }
      *(bs4*)(dst + (rt * 16 + lm) * BIGLD + cs + ct * 16 + lr) = pack4(v[0], v[1], v[2], v[3]);
    }
  }
}

// ---------- pre-kernels ----------
__global__ void node_ln_bf16(const float* __restrict__ x, const float* __restrict__ g,
                             const float* __restrict__ b, unsigned short* __restrict__ y)
{
  int row = blockIdx.x * 4 + (threadIdx.x >> 6);
  int lane = threadIdx.x & 63;
  float4 v = ((const float4*)(x + (size_t)row * HH))[lane];
  float s = v.x + v.y + v.z + v.w;
  float ss = v.x * v.x + v.y * v.y + v.z * v.z + v.w * v.w;
  #pragma unroll
  for (int m = 1; m < 64; m <<= 1) { s += __shfl_xor(s, m); ss += __shfl_xor(ss, m); }
  float mean = s * (1.f / HH);
  float var = ss * (1.f / HH) - mean * mean;
  float rstd = rsqrtf(var + 1e-5f);
  float4 gg = ((const float4*)g)[lane];
  float4 bb = ((const float4*)b)[lane];
  *(bs4*)(y + (size_t)row * HH + lane * 4) =
      pack4((v.x - mean) * rstd * gg.x + bb.x, (v.y - mean) * rstd * gg.y + bb.y,
            (v.z - mean) * rstd * gg.z + bb.z, (v.w - mean) * rstd * gg.w + bb.w);
}

__global__ void wt_transpose(const float* __restrict__ src, unsigned short* __restrict__ dst,
                             int K, int C)
{
  __shared__ float tile[32][33];
  int tx = threadIdx.x & 31, ty = threadIdx.x >> 5;
  int bk = blockIdx.x, bc = blockIdx.y;
  #pragma unroll
  for (int i = 0; i < 4; ++i)
    tile[ty + i * 8][tx] = src[(size_t)(bk * 32 + ty + i * 8) * C + bc * 32 + tx];
  __syncthreads();
  #pragma unroll
  for (int i = 0; i < 4; ++i)
    dst[(size_t)(bc * 32 + ty + i * 8) * K + bk * 32 + tx] = f2b(tile[tx][ty + i * 8]);
}

// ---------- mega kernel: 4 nodes / block, 512 threads ----------
__launch_bounds__(THREADS, 2)
__global__ void mega_kernel(P p)
{
  extern __shared__ unsigned short smem[];   // [128][BIGLD]; A = cols 0:256, B = cols 256:512

  const int tid = threadIdx.x;
  const int l = tid & 63;
  const int w = tid >> 6;           // wave 0..7
  const int lm = l & 15;
  const int lg = (l >> 4) << 3;
  const int lr = (l >> 4) << 2;
  const int n0 = blockIdx.x * NODES;
  const size_t ebase = (size_t)blockIdx.x * 128;   // global edge row base
  const int4 cnt4 = *(const int4*)(p.nbrc + n0);
  const int cnts[4] = { cnt4.x, cnt4.y, cnt4.z, cnt4.w };

  // node scratch now lives in the A region (ctx dead by the time it is used)
  #define FSA(i)  (*(float*)(smem + ((i) >> 7) * BIGLD + (((i) & 127) << 1)))
  #define FSNF(i) (*(float*)(smem + (8 + ((i) >> 7)) * BIGLD + (((i) & 127) << 1)))
  #define FLNP(j) (*(float*)(smem + 16 * BIGLD + ((j) << 1)))

  // ============ P0: stage ear -> A cols 0:128 AND gather nh -> cols 264:520 ============
  {
    int row = tid >> 2, q = tid & 3;
    const float* src = p.ear + (ebase + row) * DE + q * 32;
    unsigned short* d = smem + row * BIGLD + q * 32;
    #pragma unroll
    for (int j = 0; j < 8; ++j) {
      float4 v = ((const float4*)src)[j];
      *(bs4*)(d + j * 4) = pack4(v.x, v.y, v.z, v.w);
    }
    int idx = p.nbrl[(n0 + (row >> 5)) * KK + (row & 31)];
    const unsigned short* gsrc = p.nhb + (size_t)idx * HH + q * 64;
    unsigned short* gd = smem + row * BIGLD + 264 + q * 64;
    #pragma unroll
    for (int j = 0; j < 8; ++j) *(bs8*)(gd + j * 8) = *(const bs8*)(gsrc + j * 8);
  }
  __syncthreads();
  // ============ P1: EA: eattr = gelu(ear@Wea) -> A cols 0:256 ============
  {
    f4 acc[8][2]; zero_acc<8,2>(acc);
    gemmB<8,2,4,128>(acc, p.wtEA, smem, w * 32, l);
    __syncthreads();
    storeB<8,2,1>(smem, acc, p.b_ea, w * 32, l);
  }
  __syncthreads();
  // ============ P2: NH: nhid = gelu(nhg@Wnh) -> B cols 256:512 ============
  {
    f4 acc[8][2]; zero_acc<8,2>(acc);
    gemmB<8,2,8,256>(acc, p.wtNH, smem + 264, w * 32, l);
    __syncthreads();
    storeB<8,2,1>(smem + 256, acc, p.b_nh, w * 32, l);
  }
  __syncthreads();
  // ============ P3: GC: gate/cand (K=512) FUSED A-reads -> packed regs ============
  bs4 gp[8][2], cp[8][2];
  {
    f4 ga[8][2]; zero_acc<8,2>(ga);
    f4 ca[8][2]; zero_acc<8,2>(ca);
    gemmB2<8,2,16,512>(ga, ca, p.wtG, p.wtC, smem, w * 32, l);
    #pragma unroll
    for (int ct = 0; ct < 2; ++ct) {
      f4 bg = *(const f4*)(p.b_gate + w * 32 + ct * 16 + lr);
      f4 bc = *(const f4*)(p.b_cand + w * 32 + ct * 16 + lr);
      #pragma unroll
      for (int rt = 0; rt < 8; ++rt) {
        gp[rt][ct] = pack4(sigmoid_f(ga[rt][ct][0] + bg[0]), sigmoid_f(ga[rt][ct][1] + bg[1]),
                           sigmoid_f(ga[rt][ct][2] + bg[2]), sigmoid_f(ga[rt][ct][3] + bg[3]));
        cp[rt][ct] = pack4(fast_tanh(ca[rt][ct][0] + bc[0]), fast_tanh(ca[rt][ct][1] + bc[1]),
                           fast_tanh(ca[rt][ct][2] + bc[2]), fast_tanh(ca[rt][ct][3] + bc[3]));
      }
    }
  }
  __syncthreads();
  // ============ P4: LN1e(ef) -> A cols 0:256 ============
  {
    int row = tid >> 2, q = tid & 3;
    const float* src = p.ef + (ebase + row) * HH + q * 64;
    float s = 0.f, ss = 0.f;
    #pragma unroll
    for (int j = 0; j < 16; ++j) {
      float4 v = ((const float4*)src)[j];
      s += v.x + v.y + v.z + v.w;
      ss += v.x * v.x + v.y * v.y + v.z * v.z + v.w * v.w;
    }
    s += __shfl_xor(s, 1); ss += __shfl_xor(ss, 1);
    s += __shfl_xor(s, 2); ss += __shfl_xor(ss, 2);
    float mean = s * (1.f / HH);
    float var = ss * (1.f / HH) - mean * mean;
    float rstd = rsqrtf(var + 1e-5f);
    unsigned short* d = smem + row * BIGLD + q * 64;
    #pragma unroll
    for (int j = 0; j < 16; ++j) {
      float4 v = ((const float4*)src)[j];
      int c = q * 64 + j * 4;
      float4 g = *(const float4*)(p.ln1e_g + c);
      float4 b = *(const float4*)(p.ln1e_b + c);
      *(bs4*)(d + j * 4) = pack4((v.x - mean) * rstd * g.x + b.x,
                                 (v.y - mean) * rstd * g.y + b.y,
                                 (v.z - mean) * rstd * g.z + b.z,
                                 (v.w - mean) * rstd * g.w + b.w);
    }
  }
  __syncthreads();
  // ============ P5: EH + msg combine -> A cols 0:256 ============
  {
    f4 ea[8][2]; zero_acc<8,2>(ea);
    gemmB<8,2,8,256>(ea, p.wtEH, smem, w * 32, l);
    __syncthreads();
    #pragma unroll
    for (int ct = 0; ct < 2; ++ct) {
      f4 be = *(const f4*)(p.b_eh + w * 32 + ct * 16 + lr);
      #pragma unroll
      for (int rt = 0; rt < 8; ++rt) {
        float o[4];
        #pragma unroll
        for (int r = 0; r < 4; ++r) {
          float g = b2f((unsigned short)gp[rt][ct][r]);
          float c = b2f((unsigned short)cp[rt][ct][r]);
          float eh = gelu_f(ea[rt][ct][r] + be[r]);
          o[r] = g * c + (1.f - g) * eh;
        }
        *(bs4*)(smem + (rt * 16 + lm) * BIGLD + w * 32 + ct * 16 + lr) = pack4(o[0], o[1], o[2], o[3]);
      }
    }
  }
  __syncthreads();
  // ============ P6: QKV (V first, then Q+K fused) -> packed regs ============
  bs4 qp[8][2], kp[8][2], vp[8][2];
  {
    f4 acc[8][2]; zero_acc<8,2>(acc);
    gemmB<8,2,8,256>(acc, p.wtIN + 512 * 256, smem, w * 32, l);
    #pragma unroll
    for (int ct = 0; ct < 2; ++ct) {
      f4 bv = *(const f4*)(p.b_in + 512 + w * 32 + ct * 16 + lr);
      #pragma unroll
      for (int rt = 0; rt < 8; ++rt)
        vp[rt][ct] = pack4(acc[rt][ct][0] + bv[0], acc[rt][ct][1] + bv[1],
                           acc[rt][ct][2] + bv[2], acc[rt][ct][3] + bv[3]);
    }
    f4 accQ[8][2]; zero_acc<8,2>(accQ);
    f4 accK[8][2]; zero_acc<8,2>(accK);
    gemmB2<8,2,8,256>(accQ, accK, p.wtIN, p.wtIN + 256 * 256, smem, w * 32, l);
    #pragma unroll
    for (int ct = 0; ct < 2; ++ct) {
      f4 bq = *(const f4*)(p.b_in + w * 32 + ct * 16 + lr);
      f4 bk = *(const f4*)(p.b_in + 256 + w * 32 + ct * 16 + lr);
      #pragma unroll
      for (int rt = 0; rt < 8; ++rt) {
        qp[rt][ct] = pack4(accQ[rt][ct][0] + bq[0], accQ[rt][ct][1] + bq[1],
                           accQ[rt][ct][2] + bq[2], accQ[rt][ct][3] + bq[3]);
        kp[rt][ct] = pack4(accK[rt][ct][0] + bk[0], accK[rt][ct][1] + bk[1],
                           accK[rt][ct][2] + bk[2], accK[rt][ct][3] + bk[3]);
      }
    }
  }
  __syncthreads();   // msg (A) now dead; B scratch free
  // ============ P7: ATTENTION; ctx written per-node into A cols w*32 ============
  {
    const float asc = p.ascal[w];
    f4 z; z[0] = 0.f; z[1] = 0.f; z[2] = 0.f; z[3] = 0.f;
    #define WSADDR(a, r, c) ((w * 8 + (a) * 4 + ((r) >> 3)) * BIGLD + 256 + (((r) & 7) << 5) + (c))
    #pragma unroll
    for (int ni = 0; ni < NODES; ++ni) {
      #pragma unroll
      for (int j = 0; j < 2; ++j)
        #pragma unroll
        for (int ct = 0; ct < 2; ++ct) {
          *(bs4*)(smem + WSADDR(0, j * 16 + lm, ct * 16 + lr)) = qp[2 * ni + j][ct];
          *(bs4*)(smem + WSADDR(1, j * 16 + lm, ct * 16 + lr)) = kp[2 * ni + j][ct];
        }
      LGK_FENCE();
      bs8 qf[2], kf[2];
      #pragma unroll
      for (int t = 0; t < 2; ++t) {
        qf[t] = *(const bs8*)(smem + WSADDR(0, t * 16 + lm, lg));
        kf[t] = *(const bs8*)(smem + WSADDR(1, t * 16 + lm, lg));
      }
      f4 sc[2][2];
      #pragma unroll
      for (int kt = 0; kt < 2; ++kt)
        #pragma unroll
        for (int qt = 0; qt < 2; ++qt)
          sc[kt][qt] = __builtin_amdgcn_mfma_f32_16x16x32_bf16(kf[kt], qf[qt], z, 0, 0, 0);
      float inv[2];
      #pragma unroll
      for (int qt = 0; qt < 2; ++qt) {
        const int q = qt * 16 + lm;
        float sv[2][4];
        #pragma unroll
        for (int kt = 0; kt < 2; ++kt) {
          f4 av = *(const f4*)(p.ang + ((((size_t)(n0 + ni)) * 8 + w) * 32 + q) * 32 + kt * 16 + lr);
          #pragma unroll
          for (int r = 0; r < 4; ++r) {
            int kidx = kt * 16 + lr + r;
            sv[kt][r] = sc[kt][qt][r] * 0.17677669529663687f + av[r] * asc
                      + (kidx < cnts[ni] ? 0.f : -1e9f);
          }
        }
        float m = sv[0][0];
        #pragma unroll
        for (int r = 1; r < 4; ++r) m = fmaxf(m, sv[0][r]);
        #pragma unroll
        for (int r = 0; r < 4; ++r) m = fmaxf(m, sv[1][r]);
        m = fmaxf(m, __shfl_xor(m, 16));
        m = fmaxf(m, __shfl_xor(m, 32));
        float e[2][4], sum = 0.f;
        #pragma unroll
        for (int kt = 0; kt < 2; ++kt)
          #pragma unroll
          for (int r = 0; r < 4; ++r) { e[kt][r] = __expf(sv[kt][r] - m); sum += e[kt][r]; }
        sum += __shfl_xor(sum, 16);
        sum += __shfl_xor(sum, 32);
        inv[qt] = 1.f / sum;
        *(bs4*)(smem + WSADDR(0, q, lr))      = pack4(e[0][0], e[0][1], e[0][2], e[0][3]);
        *(bs4*)(smem + WSADDR(0, q, 16 + lr)) = pack4(e[1][0], e[1][1], e[1][2], e[1][3]);
      }
      #pragma unroll
      for (int j = 0; j < 2; ++j)
        #pragma unroll
        for (int ct = 0; ct < 2; ++ct)
          #pragma unroll
          for (int r = 0; r < 4; ++r)
            smem[WSADDR(1, ct * 16 + lr + r, j * 16 + lm)] = (unsigned short)vp[2 * ni + j][ct][r];
      LGK_FENCE();
      bs8 pf[2], vf[2];
      #pragma unroll
      for (int t = 0; t < 2; ++t) {
        pf[t] = *(const bs8*)(smem + WSADDR(0, t * 16 + lm, lg));
        vf[t] = *(const bs8*)(smem + WSADDR(1, t * 16 + lm, lg));
      }
      #pragma unroll
      for (int qt = 0; qt < 2; ++qt)
        #pragma unroll
        for (int dt = 0; dt < 2; ++dt) {
          f4 cx = __builtin_amdgcn_mfma_f32_16x16x32_bf16(vf[dt], pf[qt], z, 0, 0, 0);
          *(bs4*)(smem + (ni * 32 + qt * 16 + lm) * BIGLD + w * 32 + dt * 16 + lr) =
              pack4(cx[0] * inv[qt], cx[1] * inv[qt], cx[2] * inv[qt], cx[3] * inv[qt]);
        }
    }
    #undef WSADDR
  }
  __syncthreads();
  // ============ P9: OUT: eo = ctx(A)@Wout + b -> B cols 256:512 (disjoint) ============
  {
    f4 acc[8][2]; zero_acc<8,2>(acc);
    gemmB<8,2,8,256>(acc, p.wtOUT, smem, w * 32, l);
    storeB<8,2,0>(smem + 256, acc, p.b_out, w * 32, l);
  }
  __syncthreads();
  // ============ P10: alpha fill (eo in B) ============
  {
    #pragma unroll
    for (int it = 0; it < 2; ++it) {
      int idx = tid + it * 512;
      int ni = idx >> 8, rem = idx & 255;
      int k = rem >> 3, h = rem & 7;
      float aa = 0.f;
      #pragma unroll
      for (int j = 0; j < 8; ++j) {
        bs4 ev = *(const bs4*)(smem + (ni * 32 + k) * BIGLD + 256 + h * 32 + j * 4);
        float4 av = *(const float4*)(p.aw + h * 32 + j * 4);
        aa += b2f((unsigned short)ev[0]) * av.x + b2f((unsigned short)ev[1]) * av.y
            + b2f((unsigned short)ev[2]) * av.z + b2f((unsigned short)ev[3]) * av.w;
      }
      aa = aa > 0.f ? aa : 0.2f * aa;
      if (k >= cnts[ni]) aa = -1e9f;
      FSA(idx) = aa;
    }
  }
  __syncthreads();
  // ============ P11: alpha softmax over k: 16-lane groups ============
  {
    int ni = tid >> 7, h = (tid >> 4) & 7, l16 = tid & 15;
    float v0 = FSA(ni * 256 + l16 * 8 + h);
    float v1 = FSA(ni * 256 + (l16 + 16) * 8 + h);
    float m = fmaxf(v0, v1);
    m = fmaxf(m, __shfl_xor(m, 1));
    m = fmaxf(m, __shfl_xor(m, 2));
    m = fmaxf(m, __shfl_xor(m, 4));
    m = fmaxf(m, __shfl_xor(m, 8));
    float e0 = __expf(v0 - m), e1 = __expf(v1 - m);
    float s = e0 + e1;
    s += __shfl_xor(s, 1);
    s += __shfl_xor(s, 2);
    s += __shfl_xor(s, 4);
    s += __shfl_xor(s, 8);
    float inv = 1.f / s;
    FSA(ni * 256 + l16 * 8 + h) = e0 * inv;
    FSA(ni * 256 + (l16 + 16) * 8 + h) = e1 * inv;
  }
  __syncthreads();
  // ============ P12: aggregate: nodef + per-wave LN partials (eo in B) ============
  float ndf[2];
  {
    #pragma unroll
    for (int it = 0; it < 2; ++it) {
      int idx = it * 512 + tid;
      int ni = idx >> 8, c = idx & 255, h = c >> 5;
      float no = 0.f;
      #pragma unroll
      for (int k = 0; k < 32; ++k)
        no = fmaf(FSA(ni * 256 + k * 8 + h), b2f(smem[(ni * 32 + k) * BIGLD + 256 + c]), no);
      float nodef = no + p.nf[(size_t)(n0 + ni) * HH + c];
      ndf[it] = nodef;
      FSNF(idx) = nodef;
      float s = nodef, ss = nodef * nodef;
      #pragma unroll
      for (int m = 1; m < 64; m <<= 1) { s += __shfl_xor(s, m); ss += __shfl_xor(ss, m); }
      if (l == 0) { FLNP(it * 8 + w) = s; FLNP(16 + it * 8 + w) = ss; }
    }
  }
  __syncthreads();
  // ============ P13: LN2n -> NSTG rows 17..20 (A) ; zero rows 21..32 (A) ============
  {
    #pragma unroll
    for (int it = 0; it < 2; ++it) {
      int idx = it * 512 + tid;
      int ni = idx >> 8, c = idx & 255;
      int base = it * 8 + (ni & 1) * 4;
      float S  = FLNP(base) + FLNP(base + 1) + FLNP(base + 2) + FLNP(base + 3);
      float SS = FLNP(16 + base) + FLNP(16 + base + 1) + FLNP(16 + base + 2) + FLNP(16 + base + 3);
      float mean = S * (1.f / HH), var = SS * (1.f / HH) - mean * mean;
      float rstd = rsqrtf(var + 1e-5f);
      smem[(17 + ni) * BIGLD + c] = f2b((ndf[it] - mean) * rstd * p.ln2n_g[c] + p.ln2n_b[c]);
    }
    #pragma unroll
    for (int z = 0; z < 3; ++z) {
      int zi = z * 512 + tid;
      int zr = 21 + (zi >> 7), zc = (zi & 127) << 1;
      *(unsigned int*)(smem + zr * BIGLD + zc) = 0u;
    }
  }
  __syncthreads();
  // ============ P14: node FFN1 (A rows 17..32 -> A rows 33..64) ============
  {
    f4 acc[4];
    #pragma unroll
    for (int ct = 0; ct < 4; ++ct) { acc[ct][0]=0.f; acc[ct][1]=0.f; acc[ct][2]=0.f; acc[ct][3]=0.f; }
    #pragma unroll
    for (int kb = 0; kb < 8; ++kb) {
      bs8 afr = *(const bs8*)(smem + (17 + lm) * BIGLD + kb * 32 + lg);
      #pragma unroll
      for (int ct = 0; ct < 4; ++ct) {
        bs8 wfr = *(const bs8*)(p.wtN1 + (size_t)(w * 64 + ct * 16 + lm) * 256 + kb * 32 + lg);
        acc[ct] = __builtin_amdgcn_mfma_f32_16x16x32_bf16(wfr, afr, acc[ct], 0, 0, 0);
      }
    }
    #pragma unroll
    for (int ct = 0; ct < 4; ++ct) {
      int col = w * 64 + ct * 16 + lr;
      f4 bv = *(const f4*)(p.bn1 + col);
      *(bs4*)(smem + (33 + 2 * lm + (col >= 256 ? 1 : 0)) * BIGLD + (col & 255)) =
          pack4(gelu_f(acc[ct][0] + bv[0]), gelu_f(acc[ct][1] + bv[1]),
                gelu_f(acc[ct][2] + bv[2]), gelu_f(acc[ct][3] + bv[3]));
    }
  }
  __syncthreads();
  // ============ P15: node FFN2 + residual -> on ; pack edge_f regs (eo in B) ============
  bs4 efp[8][2];
  {
    f4 acc[2];
    #pragma unroll
    for (int ct = 0; ct < 2; ++ct) { acc[ct][0]=0.f; acc[ct][1]=0.f; acc[ct][2]=0.f; acc[ct][3]=0.f; }
    #pragma unroll
    for (int kb = 0; kb < 16; ++kb) {
      bs8 afr = *(const bs8*)(smem + (33 + 2 * lm + (kb >> 3)) * BIGLD + (kb & 7) * 32 + lg);
      #pragma unroll
      for (int ct = 0; ct < 2; ++ct) {
        bs8 wfr = *(const bs8*)(p.wtN2 + (size_t)(w * 32 + ct * 16 + lm) * 512 + kb * 32 + lg);
        acc[ct] = __builtin_amdgcn_mfma_f32_16x16x32_bf16(wfr, afr, acc[ct], 0, 0, 0);
      }
    }
    if (lm < 4) {
      #pragma unroll
      for (int ct = 0; ct < 2; ++ct) {
        int col = w * 32 + ct * 16 + lr;
        f4 bv = *(const f4*)(p.bn2 + col);
        float4 o;
        o.x = acc[ct][0] + bv[0] + FSNF(lm * 256 + col);
        o.y = acc[ct][1] + bv[1] + FSNF(lm * 256 + col + 1);
        o.z = acc[ct][2] + bv[2] + FSNF(lm * 256 + col + 2);
        o.w = acc[ct][3] + bv[3] + FSNF(lm * 256 + col + 3);
        *(float4*)(p.on + (size_t)(n0 + lm) * HH + col) = o;
      }
    }
    #pragma unroll
    for (int rt = 0; rt < 8; ++rt)
      #pragma unroll
      for (int ct = 0; ct < 2; ++ct) {
        int row = rt * 16 + lm, col = w * 32 + ct * 16 + lr;
        bs4 ov = *(const bs4*)(smem + row * BIGLD + 256 + col);
        float4 e = *(const float4*)(p.ef + (ebase + row) * HH + col);
        efp[rt][ct] = pack4(e.x + b2f((unsigned short)ov[0]), e.y + b2f((unsigned short)ov[1]),
                            e.z + b2f((unsigned short)ov[2]), e.w + b2f((unsigned short)ov[3]));
      }
  }
  __syncthreads();
  // ============ P16: LN2e(eo(B) + ef) -> A cols 0:256 ============
  {
    int row = tid >> 2, q = tid & 3;
    const float* efs = p.ef + (ebase + row) * HH + q * 64;
    const unsigned short* eor = smem + row * BIGLD + 256 + q * 64;
    float xv[64];
    float s = 0.f, ss = 0.f;
    #pragma unroll
    for (int j = 0; j < 16; ++j) {
      float4 e = ((const float4*)efs)[j];
      bs4 ov = *(const bs4*)(eor + j * 4);
      float x0 = e.x + b2f((unsigned short)ov[0]);
      float x1 = e.y + b2f((unsigned short)ov[1]);
      float x2 = e.z + b2f((unsigned short)ov[2]);
      float x3 = e.w + b2f((unsigned short)ov[3]);
      xv[j * 4] = x0; xv[j * 4 + 1] = x1; xv[j * 4 + 2] = x2; xv[j * 4 + 3] = x3;
      s += x0 + x1 + x2 + x3;
      ss += x0 * x0 + x1 * x1 + x2 * x2 + x3 * x3;
    }
    s += __shfl_xor(s, 1); ss += __shfl_xor(ss, 1);
    s += __shfl_xor(s, 2); ss += __shfl_xor(ss, 2);
    float mean = s * (1.f / HH);
    float var = ss * (1.f / HH) - mean * mean;
    float rstd = rsqrtf(var + 1e-5f);
    unsigned short* d = smem + row * BIGLD + q * 64;
    #pragma unroll
    for (int j = 0; j < 16; ++j) {
      int c = q * 64 + j * 4;
      float4 g = *(const float4*)(p.ln2e_g + c);
      float4 b = *(const float4*)(p.ln2e_b + c);
      *(bs4*)(d + j * 4) = pack4((xv[j * 4] - mean) * rstd * g.x + b.x,
                                 (xv[j * 4 + 1] - mean) * rstd * g.y + b.y,
                                 (xv[j * 4 + 2] - mean) * rstd * g.z + b.z,
                                 (xv[j * 4 + 3] - mean) * rstd * g.w + b.w);
    }
  }
  __syncthreads();
  // ============ P17: E1 half0 (reads A, stores B: no inner barrier; eo dead) ============
  f4 oacc[8][2]; zero_acc<8,2>(oacc);
  {
    f4 h[8][2]; zero_acc<8,2>(h);
    gemmB<8,2,8,256>(h, p.wtE1, smem, w * 32, l);
    storeB<8,2,1>(smem + 256, h, p.be1, w * 32, l);
  }
  __syncthreads();
  // ============ P18: E2 part0 + E1 half1 ; inner barrier ; E1b store ============
  {
    gemmB<8,2,8,512>(oacc, p.wtE2, smem + 256, w * 32, l);
    f4 h[8][2]; zero_acc<8,2>(h);
    gemmB<8,2,8,256>(h, p.wtE1 + (size_t)256 * 256, smem, w * 32, l);
    __syncthreads();
    storeB<8,2,1>(smem + 256, h, p.be1 + 256, w * 32, l);
  }
  __syncthreads();
  // ============ P19: E2 part1 + epilogue -> oe ============
  {
    gemmB<8,2,8,512>(oacc, p.wtE2 + 256, smem + 256, w * 32, l);
    #pragma unroll
    for (int ct = 0; ct < 2; ++ct) {
      f4 bv = *(const f4*)(p.be2 + w * 32 + ct * 16 + lr);
      #pragma unroll
      for (int rt = 0; rt < 8; ++rt) {
        int row = rt * 16 + lm;
        float4 o;
        o.x = oacc[rt][ct][0] + bv[0] + b2f((unsigned short)efp[rt][ct][0]);
        o.y = oacc[rt][ct][1] + bv[1] + b2f((unsigned short)efp[rt][ct][1]);
        o.z = oacc[rt][ct][2] + bv[2] + b2f((unsigned short)efp[rt][ct][2]);
        o.w = oacc[rt][ct][3] + bv[3] + b2f((unsigned short)efp[rt][ct][3]);
        *(float4*)(p.oe + (ebase + row) * HH + w * 32 + ct * 16 + lr) = o;
      }
    }
  }
  #undef FSA
  #undef FSNF
  #undef FLNP
}

extern "C" void kernel_launch(void* const* d_in, const int* in_sizes, int n_in,
                              void* d_out, int out_size, void* d_ws, size_t ws_size,
                              hipStream_t stream)
{
  P p;
  p.nf     = (const float*)d_in[0];
  p.ef     = (const float*)d_in[1];
  p.ear    = (const float*)d_in[2];
  p.ang    = (const float*)d_in[3];
  const float* ln1n_g = (const float*)d_in[4];
  const float* ln1n_b = (const float*)d_in[5];
  p.ln1e_g = (const float*)d_in[6];  p.ln1e_b = (const float*)d_in[7];
  const float* W_ea   = (const float*)d_in[8];  p.b_ea   = (const float*)d_in[9];
  const float* W_nh   = (const float*)d_in[10]; p.b_nh   = (const float*)d_in[11];
  const float* W_eh   = (const float*)d_in[12]; p.b_eh   = (const float*)d_in[13];
  const float* W_gate = (const float*)d_in[14]; p.b_gate = (const float*)d_in[15];
  const float* W_cand = (const float*)d_in[16]; p.b_cand = (const float*)d_in[17];
  p.ascal  = (const float*)d_in[18];
  const float* W_in   = (const float*)d_in[19]; p.b_in   = (const float*)d_in[20];
  const float* W_out  = (const float*)d_in[21]; p.b_out  = (const float*)d_in[22];
  p.aw     = (const float*)d_in[23];
  p.ln2n_g = (const float*)d_in[24]; p.ln2n_b = (const float*)d_in[25];
  p.ln2e_g = (const float*)d_in[26]; p.ln2e_b = (const float*)d_in[27];
  const float* Wn1 = (const float*)d_in[28]; p.bn1 = (const float*)d_in[29];
  const float* Wn2 = (const float*)d_in[30]; p.bn2 = (const float*)d_in[31];
  const float* We1 = (const float*)d_in[32]; p.be1 = (const float*)d_in[33];
  const float* We2 = (const float*)d_in[34]; p.be2 = (const float*)d_in[35];
  p.nbrl   = (const int*)d_in[36];
  p.nbrc   = (const int*)d_in[37];
  p.on     = (float*)d_out;
  p.oe     = (float*)d_out + (size_t)NN * HH;

  size_t off = 0;
  auto alloc = [&](size_t elems) {
    unsigned short* q = (unsigned short*)((char*)d_ws + off);
    off += elems * 2;
    return q;
  };
  unsigned short* nhb = alloc((size_t)NN * HH);
  unsigned short* wtEA  = alloc(256 * 128);
  unsigned short* wtNH  = alloc(256 * 256);
  unsigned short* wtEH  = alloc(256 * 256);
  unsigned short* wtG   = alloc(256 * 512);
  unsigned short* wtC   = alloc(256 * 512);
  unsigned short* wtIN  = alloc(768 * 256);
  unsigned short* wtOUT = alloc(256 * 256);
  unsigned short* wtN1  = alloc(512 * 256);
  unsigned short* wtN2  = alloc(256 * 512);
  unsigned short* wtE1  = alloc(512 * 256);
  unsigned short* wtE2  = alloc(256 * 512);
  p.nhb = nhb;
  p.wtEA = wtEA; p.wtNH = wtNH; p.wtEH = wtEH; p.wtG = wtG; p.wtC = wtC;
  p.wtIN = wtIN; p.wtOUT = wtOUT; p.wtN1 = wtN1; p.wtN2 = wtN2; p.wtE1 = wtE1; p.wtE2 = wtE2;

  node_ln_bf16<<<NN / 4, 256, 0, stream>>>((const float*)d_in[0], ln1n_g, ln1n_b, nhb);

  auto tr = [&](const float* src, unsigned short* dst, int K, int C) {
    wt_transpose<<<dim3(K / 32, C / 32), 256, 0, stream>>>(src, dst, K, C);
  };
  tr(W_ea, wtEA, 128, 256);
  tr(W_nh, wtNH, 256, 256);
  tr(W_eh, wtEH, 256, 256);
  tr(W_gate, wtG, 512, 256);
  tr(W_cand, wtC, 512, 256);
  tr(W_in, wtIN, 256, 768);
  tr(W_out, wtOUT, 256, 256);
  tr(Wn1, wtN1, 256, 512);
  tr(Wn2, wtN2, 512, 256);
  tr(We1, wtE1, 256, 512);
  tr(We2, wtE2, 512, 256);

  (void)hipFuncSetAttribute((const void*)mega_kernel,
                            hipFuncAttributeMaxDynamicSharedMemorySize, LDS_BYTES);
  mega_kernel<<<NN / NODES, THREADS, LDS_BYTES, stream>>>(p);
}

// Round 17
// 1446.808 us; speedup vs baseline: 1.0151x; 1.0151x over previous
//
#include <hip/hip_runtime.h>
#include <math.h>

#define NN 8000
#define KK 32
#define HH 256
#define DE 128
#define NODES 4
#define THREADS 512
#define BIGLD 536
#define LDS_BYTES (128 * BIGLD * 2)

typedef __attribute__((ext_vector_type(8))) short bs8;
typedef __attribute__((ext_vector_type(4))) short bs4;
typedef __attribute__((ext_vector_type(4))) float f4;

#define LGK_FENCE() do { asm volatile("s_waitcnt lgkmcnt(0)" ::: "memory"); __builtin_amdgcn_sched_barrier(0); } while (0)

struct P {
  const float *nf, *ef, *ear, *ang;
  const float *ln1e_g, *ln1e_b;
  const float *b_ea, *b_nh, *b_eh, *b_gate, *b_cand;
  const float *ascal, *b_in, *b_out, *aw;
  const float *ln2n_g, *ln2n_b, *ln2e_g, *ln2e_b;
  const float *bn1, *bn2, *be1, *be2;
  const int *nbrl, *nbrc;
  const unsigned short *nhb;
  const unsigned short *wtEA, *wtNH, *wtEH, *wtG, *wtC, *wtIN, *wtOUT, *wtN1, *wtN2, *wtE1, *wtE2;
  float *on, *oe;
};

__device__ __forceinline__ unsigned short f2b(float f) {
  unsigned int u = __float_as_uint(f);
  unsigned int r = (u + 0x7fffu + ((u >> 16) & 1u)) >> 16;
  return (unsigned short)r;
}
__device__ __forceinline__ float b2f(unsigned short u) {
  return __uint_as_float(((unsigned int)u) << 16);
}
__device__ __forceinline__ unsigned int cvt_pk_bf16(float lo, float hi) {
  unsigned int r;
  asm("v_cvt_pk_bf16_f32 %0, %1, %2" : "=v"(r) : "v"(lo), "v"(hi));
  return r;
}
__device__ __forceinline__ bs4 pack4(float a, float b, float c, float d) {
  union { unsigned int u[2]; bs4 v; } x;
  x.u[0] = cvt_pk_bf16(a, b);
  x.u[1] = cvt_pk_bf16(c, d);
  return x.v;
}
__device__ __forceinline__ float fast_tanh(float x) {
  x = fminf(fmaxf(x, -12.f), 12.f);
  float e = __expf(2.f * x);
  return (e - 1.f) / (e + 1.f);
}
__device__ __forceinline__ float gelu_f(float x) {
  return 0.5f * x * (1.f + fast_tanh(0.7978845608f * (x + 0.044715f * x * x * x)));
}
__device__ __forceinline__ float sigmoid_f(float x) {
  return 1.f / (1.f + __expf(-x));
}

// acc[rt][ct] = mfma(Wfrag, Afrag): out row (A-row) = rt*16+(l&15),
// out col = cs + ct*16 + (l>>4)*4 + r. A in LDS stride BIGLD. W [outcol][KW].
template<int RT, int NCT, int KB, int KW>
__device__ __forceinline__ void gemmB(f4 acc[RT][NCT],
    const unsigned short* __restrict__ wt,
    const unsigned short* __restrict__ A, int cs, int l)
{
  const int lm = l & 15;
  const int lg = (l >> 4) << 3;
  #pragma unroll
  for (int kb = 0; kb < KB; ++kb) {
    bs8 wfr[NCT];
    #pragma unroll
    for (int ct = 0; ct < NCT; ++ct)
      wfr[ct] = *(const bs8*)(wt + (size_t)(cs + ct * 16 + lm) * KW + kb * 32 + lg);
    bs8 afr[RT];
    #pragma unroll
    for (int rt = 0; rt < RT; ++rt)
      afr[rt] = *(const bs8*)(A + (rt * 16 + lm) * BIGLD + kb * 32 + lg);
    #pragma unroll
    for (int rt = 0; rt < RT; ++rt)
      #pragma unroll
      for (int ct = 0; ct < NCT; ++ct)
        acc[rt][ct] = __builtin_amdgcn_mfma_f32_16x16x32_bf16(wfr[ct], afr[rt], acc[rt][ct], 0, 0, 0);
  }
}

// Dual-accumulator variant: two weight streams share one A-fragment load.
template<int RT, int NCT, int KB, int KW>
__device__ __forceinline__ void gemmB2(f4 acc0[RT][NCT], f4 acc1[RT][NCT],
    const unsigned short* __restrict__ wt0,
    const unsigned short* __restrict__ wt1,
    const unsigned short* __restrict__ A, int cs, int l)
{
  const int lm = l & 15;
  const int lg = (l >> 4) << 3;
  #pragma unroll
  for (int kb = 0; kb < KB; ++kb) {
    bs8 wfr0[NCT], wfr1[NCT];
    #pragma unroll
    for (int ct = 0; ct < NCT; ++ct) {
      wfr0[ct] = *(const bs8*)(wt0 + (size_t)(cs + ct * 16 + lm) * KW + kb * 32 + lg);
      wfr1[ct] = *(const bs8*)(wt1 + (size_t)(cs + ct * 16 + lm) * KW + kb * 32 + lg);
    }
    bs8 afr[RT];
    #pragma unroll
    for (int rt = 0; rt < RT; ++rt)
      afr[rt] = *(const bs8*)(A + (rt * 16 + lm) * BIGLD + kb * 32 + lg);
    #pragma unroll
    for (int rt = 0; rt < RT; ++rt)
      #pragma unroll
      for (int ct = 0; ct < NCT; ++ct) {
        acc0[rt][ct] = __builtin_amdgcn_mfma_f32_16x16x32_bf16(wfr0[ct], afr[rt], acc0[rt][ct], 0, 0, 0);
        acc1[rt][ct] = __builtin_amdgcn_mfma_f32_16x16x32_bf16(wfr1[ct], afr[rt], acc1[rt][ct], 0, 0, 0);
      }
  }
}

template<int RT, int NCT>
__device__ __forceinline__ void zero_acc(f4 acc[RT][NCT]) {
  #pragma unroll
  for (int rt = 0; rt < RT; ++rt)
    #pragma unroll
    for (int ct = 0; ct < NCT; ++ct) {
      acc[rt][ct][0] = 0.f; acc[rt][ct][1] = 0.f; acc[rt][ct][2] = 0.f; acc[rt][ct][3] = 0.f;
    }
}

template<int RT, int NCT, int ACTF>
__device__ __forceinline__ void storeB(unsigned short* dst,
    f4 acc[RT][NCT], const float* __restrict__ bias, int cs, int l)
{
  const int lm = l & 15;
  const int lr = (l >> 4) << 2;
  #pragma unroll
  for (int ct = 0; ct < NCT; ++ct) {
    f4 bv = *(const f4*)(bias + cs + ct * 16 + lr);
    #pragma unroll
    for (int rt = 0; rt < RT; ++rt) {
      float v[4];
      #pragma unroll
      for (int r = 0; r < 4; ++r) {
        v[r] = acc[rt][ct][r] + bv[r];
        if (ACTF == 1) v[r] = gelu_f(v[r]);
      }
      *(bs4*)(dst + (rt * 16 + lm) * BIGLD + cs + ct * 16 + lr) = pack4(v[0], v[1], v[2], v[3]);
    }
  }
}

// ---------- pre-kernels ----------
__global__ void node_ln_bf16(const float* __restrict__ x, const float* __restrict__ g,
                             const float* __restrict__ b, unsigned short* __restrict__ y)
{
  int row = blockIdx.x * 4 + (threadIdx.x >> 6);
  int lane = threadIdx.x & 63;
  float4 v = ((const float4*)(x + (size_t)row * HH))[lane];
  float s = v.x + v.y + v.z + v.w;
  float ss = v.x * v.x + v.y * v.y + v.z * v.z + v.w * v.w;
  #pragma unroll
  for (int m = 1; m < 64; m <<= 1) { s += __shfl_xor(s, m); ss += __shfl_xor(ss, m); }
  float mean = s * (1.f / HH);
  float var = ss * (1.f / HH) - mean * mean;
  float rstd = rsqrtf(var + 1e-5f);
  float4 gg = ((const float4*)g)[lane];
  float4 bb = ((const float4*)b)[lane];
  *(bs4*)(y + (size_t)row * HH + lane * 4) =
      pack4((v.x - mean) * rstd * gg.x + bb.x, (v.y - mean) * rstd * gg.y + bb.y,
            (v.z - mean) * rstd * gg.z + bb.z, (v.w - mean) * rstd * gg.w + bb.w);
}

__global__ void wt_transpose(const float* __restrict__ src, unsigned short* __restrict__ dst,
                             int K, int C)
{
  __shared__ float tile[32][33];
  int tx = threadIdx.x & 31, ty = threadIdx.x >> 5;
  int bk = blockIdx.x, bc = blockIdx.y;
  #pragma unroll
  for (int i = 0; i < 4; ++i)
    tile[ty + i * 8][tx] = src[(size_t)(bk * 32 + ty + i * 8) * C + bc * 32 + tx];
  __syncthreads();
  #pragma unroll
  for (int i = 0; i < 4; ++i)
    dst[(size_t)(bc * 32 + ty + i * 8) * K + bk * 32 + tx] = f2b(tile[tx][ty + i * 8]);
}

// ---------- mega kernel: 4 nodes / block, 512 threads ----------
__launch_bounds__(THREADS, 2)
__global__ void mega_kernel(P p)
{
  extern __shared__ unsigned short smem[];   // [128][BIGLD]

  const int tid = threadIdx.x;
  const int l = tid & 63;
  const int w = tid >> 6;           // wave 0..7
  const int lm = l & 15;
  const int lg = (l >> 4) << 3;
  const int lr = (l >> 4) << 2;
  const int n0 = blockIdx.x * NODES;
  const size_t ebase = (size_t)blockIdx.x * 128;   // global edge row base
  const int4 cnt4 = *(const int4*)(p.nbrc + n0);
  const int cnts[4] = { cnt4.x, cnt4.y, cnt4.z, cnt4.w };

  #define FSA(i)  (*(float*)(smem + ((i) >> 7) * BIGLD + 256 + (((i) & 127) << 1)))
  #define FSNF(i) (*(float*)(smem + (8 + ((i) >> 7)) * BIGLD + 256 + (((i) & 127) << 1)))
  #define FLNP(j) (*(float*)(smem + 16 * BIGLD + 256 + ((j) << 1)))

  // ============ P0: stage ear -> cols 0:128 AND gather nh -> cols 264:520 ============
  {
    int row = tid >> 2, q = tid & 3;
    const float* src = p.ear + (ebase + row) * DE + q * 32;
    unsigned short* d = smem + row * BIGLD + q * 32;
    #pragma unroll
    for (int j = 0; j < 8; ++j) {
      float4 v = ((const float4*)src)[j];
      *(bs4*)(d + j * 4) = pack4(v.x, v.y, v.z, v.w);
    }
    int idx = p.nbrl[(n0 + (row >> 5)) * KK + (row & 31)];
    const unsigned short* gsrc = p.nhb + (size_t)idx * HH + q * 64;
    unsigned short* gd = smem + row * BIGLD + 264 + q * 64;
    #pragma unroll
    for (int j = 0; j < 8; ++j) *(bs8*)(gd + j * 8) = *(const bs8*)(gsrc + j * 8);
  }
  __syncthreads();
  // ============ P1: EA: eattr = gelu(ear@Wea) -> cols 0:256 (acc-then-store) ============
  {
    f4 acc[8][2]; zero_acc<8,2>(acc);
    gemmB<8,2,4,128>(acc, p.wtEA, smem, w * 32, l);
    __syncthreads();
    storeB<8,2,1>(smem, acc, p.b_ea, w * 32, l);
  }
  __syncthreads();
  // ============ P2: NH: nhid = gelu(nhg@Wnh) -> cols 256:512 ============
  {
    f4 acc[8][2]; zero_acc<8,2>(acc);
    gemmB<8,2,8,256>(acc, p.wtNH, smem + 264, w * 32, l);
    __syncthreads();
    storeB<8,2,1>(smem + 256, acc, p.b_nh, w * 32, l);
  }
  __syncthreads();
  // ============ P3: GC: gate/cand (K=512) FUSED A-reads -> packed regs ============
  bs4 gp[8][2], cp[8][2];
  {
    f4 ga[8][2]; zero_acc<8,2>(ga);
    f4 ca[8][2]; zero_acc<8,2>(ca);
    gemmB2<8,2,16,512>(ga, ca, p.wtG, p.wtC, smem, w * 32, l);
    #pragma unroll
    for (int ct = 0; ct < 2; ++ct) {
      f4 bg = *(const f4*)(p.b_gate + w * 32 + ct * 16 + lr);
      f4 bc = *(const f4*)(p.b_cand + w * 32 + ct * 16 + lr);
      #pragma unroll
      for (int rt = 0; rt < 8; ++rt) {
        gp[rt][ct] = pack4(sigmoid_f(ga[rt][ct][0] + bg[0]), sigmoid_f(ga[rt][ct][1] + bg[1]),
                           sigmoid_f(ga[rt][ct][2] + bg[2]), sigmoid_f(ga[rt][ct][3] + bg[3]));
        cp[rt][ct] = pack4(fast_tanh(ca[rt][ct][0] + bc[0]), fast_tanh(ca[rt][ct][1] + bc[1]),
                           fast_tanh(ca[rt][ct][2] + bc[2]), fast_tanh(ca[rt][ct][3] + bc[3]));
      }
    }
  }
  __syncthreads();
  // ============ P4: LN1e(ef) -> cols 0:256 ============
  {
    int row = tid >> 2, q = tid & 3;
    const float* src = p.ef + (ebase + row) * HH + q * 64;
    float s = 0.f, ss = 0.f;
    #pragma unroll
    for (int j = 0; j < 16; ++j) {
      float4 v = ((const float4*)src)[j];
      s += v.x + v.y + v.z + v.w;
      ss += v.x * v.x + v.y * v.y + v.z * v.z + v.w * v.w;
    }
    s += __shfl_xor(s, 1); ss += __shfl_xor(ss, 1);
    s += __shfl_xor(s, 2); ss += __shfl_xor(ss, 2);
    float mean = s * (1.f / HH);
    float var = ss * (1.f / HH) - mean * mean;
    float rstd = rsqrtf(var + 1e-5f);
    unsigned short* d = smem + row * BIGLD + q * 64;
    #pragma unroll
    for (int j = 0; j < 16; ++j) {
      float4 v = ((const float4*)src)[j];
      int c = q * 64 + j * 4;
      float4 g = *(const float4*)(p.ln1e_g + c);
      float4 b = *(const float4*)(p.ln1e_b + c);
      *(bs4*)(d + j * 4) = pack4((v.x - mean) * rstd * g.x + b.x,
                                 (v.y - mean) * rstd * g.y + b.y,
                                 (v.z - mean) * rstd * g.z + b.z,
                                 (v.w - mean) * rstd * g.w + b.w);
    }
  }
  __syncthreads();
  // ============ P5: EH + msg combine -> cols 0:256 ============
  {
    f4 ea[8][2]; zero_acc<8,2>(ea);
    gemmB<8,2,8,256>(ea, p.wtEH, smem, w * 32, l);
    __syncthreads();
    #pragma unroll
    for (int ct = 0; ct < 2; ++ct) {
      f4 be = *(const f4*)(p.b_eh + w * 32 + ct * 16 + lr);
      #pragma unroll
      for (int rt = 0; rt < 8; ++rt) {
        float o[4];
        #pragma unroll
        for (int r = 0; r < 4; ++r) {
          float g = b2f((unsigned short)gp[rt][ct][r]);
          float c = b2f((unsigned short)cp[rt][ct][r]);
          float eh = gelu_f(ea[rt][ct][r] + be[r]);
          o[r] = g * c + (1.f - g) * eh;
        }
        *(bs4*)(smem + (rt * 16 + lm) * BIGLD + w * 32 + ct * 16 + lr) = pack4(o[0], o[1], o[2], o[3]);
      }
    }
  }
  __syncthreads();
  // ============ P6: QKV -> packed regs (wave w = head w); Q+K FUSED A-reads ============
  bs4 qp[8][2], kp[8][2], vp[8][2];
  {
    f4 accQ[8][2]; zero_acc<8,2>(accQ);
    f4 accK[8][2]; zero_acc<8,2>(accK);
    gemmB2<8,2,8,256>(accQ, accK, p.wtIN, p.wtIN + 256 * 256, smem, w * 32, l);
    #pragma unroll
    for (int ct = 0; ct < 2; ++ct) {
      f4 bq = *(const f4*)(p.b_in + w * 32 + ct * 16 + lr);
      f4 bk = *(const f4*)(p.b_in + 256 + w * 32 + ct * 16 + lr);
      #pragma unroll
      for (int rt = 0; rt < 8; ++rt) {
        qp[rt][ct] = pack4(accQ[rt][ct][0] + bq[0], accQ[rt][ct][1] + bq[1],
                           accQ[rt][ct][2] + bq[2], accQ[rt][ct][3] + bq[3]);
        kp[rt][ct] = pack4(accK[rt][ct][0] + bk[0], accK[rt][ct][1] + bk[1],
                           accK[rt][ct][2] + bk[2], accK[rt][ct][3] + bk[3]);
      }
    }
    f4 acc[8][2]; zero_acc<8,2>(acc);
    gemmB<8,2,8,256>(acc, p.wtIN + 512 * 256, smem, w * 32, l);
    #pragma unroll
    for (int ct = 0; ct < 2; ++ct) {
      f4 bv = *(const f4*)(p.b_in + 512 + w * 32 + ct * 16 + lr);
      #pragma unroll
      for (int rt = 0; rt < 8; ++rt)
        vp[rt][ct] = pack4(acc[rt][ct][0] + bv[0], acc[rt][ct][1] + bv[1],
                           acc[rt][ct][2] + bv[2], acc[rt][ct][3] + bv[3]);
    }
  }
  __syncthreads();
  // ============ P7: ATTENTION (wave w = head w, 4 nodes sequential) ============
  bs4 cxp[NODES][2][2];
  {
    const float asc = p.ascal[w];
    f4 z; z[0] = 0.f; z[1] = 0.f; z[2] = 0.f; z[3] = 0.f;
    #define WSADDR(a, r, c) ((w * 8 + (a) * 4 + ((r) >> 3)) * BIGLD + 256 + (((r) & 7) << 5) + (c))
    #pragma unroll
    for (int ni = 0; ni < NODES; ++ni) {
      #pragma unroll
      for (int j = 0; j < 2; ++j)
        #pragma unroll
        for (int ct = 0; ct < 2; ++ct) {
          *(bs4*)(smem + WSADDR(0, j * 16 + lm, ct * 16 + lr)) = qp[2 * ni + j][ct];
          *(bs4*)(smem + WSADDR(1, j * 16 + lm, ct * 16 + lr)) = kp[2 * ni + j][ct];
        }
      LGK_FENCE();
      bs8 qf[2], kf[2];
      #pragma unroll
      for (int t = 0; t < 2; ++t) {
        qf[t] = *(const bs8*)(smem + WSADDR(0, t * 16 + lm, lg));
        kf[t] = *(const bs8*)(smem + WSADDR(1, t * 16 + lm, lg));
      }
      f4 sc[2][2];
      #pragma unroll
      for (int kt = 0; kt < 2; ++kt)
        #pragma unroll
        for (int qt = 0; qt < 2; ++qt)
          sc[kt][qt] = __builtin_amdgcn_mfma_f32_16x16x32_bf16(kf[kt], qf[qt], z, 0, 0, 0);
      float inv[2];
      #pragma unroll
      for (int qt = 0; qt < 2; ++qt) {
        const int q = qt * 16 + lm;
        float sv[2][4];
        #pragma unroll
        for (int kt = 0; kt < 2; ++kt) {
          f4 av = *(const f4*)(p.ang + ((((size_t)(n0 + ni)) * 8 + w) * 32 + q) * 32 + kt * 16 + lr);
          #pragma unroll
          for (int r = 0; r < 4; ++r) {
            int kidx = kt * 16 + lr + r;
            sv[kt][r] = sc[kt][qt][r] * 0.17677669529663687f + av[r] * asc
                      + (kidx < cnts[ni] ? 0.f : -1e9f);
          }
        }
        float m = sv[0][0];
        #pragma unroll
        for (int r = 1; r < 4; ++r) m = fmaxf(m, sv[0][r]);
        #pragma unroll
        for (int r = 0; r < 4; ++r) m = fmaxf(m, sv[1][r]);
        m = fmaxf(m, __shfl_xor(m, 16));
        m = fmaxf(m, __shfl_xor(m, 32));
        float e[2][4], sum = 0.f;
        #pragma unroll
        for (int kt = 0; kt < 2; ++kt)
          #pragma unroll
          for (int r = 0; r < 4; ++r) { e[kt][r] = __expf(sv[kt][r] - m); sum += e[kt][r]; }
        sum += __shfl_xor(sum, 16);
        sum += __shfl_xor(sum, 32);
        inv[qt] = 1.f / sum;
        *(bs4*)(smem + WSADDR(0, q, lr))      = pack4(e[0][0], e[0][1], e[0][2], e[0][3]);
        *(bs4*)(smem + WSADDR(0, q, 16 + lr)) = pack4(e[1][0], e[1][1], e[1][2], e[1][3]);
      }
      #pragma unroll
      for (int j = 0; j < 2; ++j)
        #pragma unroll
        for (int ct = 0; ct < 2; ++ct)
          #pragma unroll
          for (int r = 0; r < 4; ++r)
            smem[WSADDR(1, ct * 16 + lr + r, j * 16 + lm)] = (unsigned short)vp[2 * ni + j][ct][r];
      LGK_FENCE();
      bs8 pf[2], vf[2];
      #pragma unroll
      for (int t = 0; t < 2; ++t) {
        pf[t] = *(const bs8*)(smem + WSADDR(0, t * 16 + lm, lg));
        vf[t] = *(const bs8*)(smem + WSADDR(1, t * 16 + lm, lg));
      }
      #pragma unroll
      for (int qt = 0; qt < 2; ++qt)
        #pragma unroll
        for (int dt = 0; dt < 2; ++dt) {
          f4 cx = __builtin_amdgcn_mfma_f32_16x16x32_bf16(vf[dt], pf[qt], z, 0, 0, 0);
          cxp[ni][qt][dt] = pack4(cx[0] * inv[qt], cx[1] * inv[qt], cx[2] * inv[qt], cx[3] * inv[qt]);
        }
    }
    #undef WSADDR
  }
  __syncthreads();
  // ============ P8: ctx -> cols 256:512 ============
  {
    #pragma unroll
    for (int ni = 0; ni < NODES; ++ni)
      #pragma unroll
      for (int qt = 0; qt < 2; ++qt)
        #pragma unroll
        for (int dt = 0; dt < 2; ++dt)
          *(bs4*)(smem + (ni * 32 + qt * 16 + lm) * BIGLD + 256 + w * 32 + dt * 16 + lr) = cxp[ni][qt][dt];
  }
  __syncthreads();
  // ============ P9: OUT: eo = ctx@Wout + b -> cols 0:256 (disjoint: no inner barrier) ============
  {
    f4 acc[8][2]; zero_acc<8,2>(acc);
    gemmB<8,2,8,256>(acc, p.wtOUT, smem + 256, w * 32, l);
    storeB<8,2,0>(smem, acc, p.b_out, w * 32, l);
  }
  __syncthreads();
  // ============ P10: alpha fill ============
  {
    #pragma unroll
    for (int it = 0; it < 2; ++it) {
      int idx = tid + it * 512;
      int ni = idx >> 8, rem = idx & 255;
      int k = rem >> 3, h = rem & 7;
      float aa = 0.f;
      #pragma unroll
      for (int j = 0; j < 8; ++j) {
        bs4 ev = *(const bs4*)(smem + (ni * 32 + k) * BIGLD + h * 32 + j * 4);
        float4 av = *(const float4*)(p.aw + h * 32 + j * 4);
        aa += b2f((unsigned short)ev[0]) * av.x + b2f((unsigned short)ev[1]) * av.y
            + b2f((unsigned short)ev[2]) * av.z + b2f((unsigned short)ev[3]) * av.w;
      }
      aa = aa > 0.f ? aa : 0.2f * aa;
      if (k >= cnts[ni]) aa = -1e9f;
      FSA(idx) = aa;
    }
  }
  __syncthreads();
  // ============ P11: alpha softmax over k: 16-lane groups ============
  {
    int ni = tid >> 7, h = (tid >> 4) & 7, l16 = tid & 15;
    float v0 = FSA(ni * 256 + l16 * 8 + h);
    float v1 = FSA(ni * 256 + (l16 + 16) * 8 + h);
    float m = fmaxf(v0, v1);
    m = fmaxf(m, __shfl_xor(m, 1));
    m = fmaxf(m, __shfl_xor(m, 2));
    m = fmaxf(m, __shfl_xor(m, 4));
    m = fmaxf(m, __shfl_xor(m, 8));
    float e0 = __expf(v0 - m), e1 = __expf(v1 - m);
    float s = e0 + e1;
    s += __shfl_xor(s, 1);
    s += __shfl_xor(s, 2);
    s += __shfl_xor(s, 4);
    s += __shfl_xor(s, 8);
    float inv = 1.f / s;
    FSA(ni * 256 + l16 * 8 + h) = e0 * inv;
    FSA(ni * 256 + (l16 + 16) * 8 + h) = e1 * inv;
  }
  __syncthreads();
  // ============ P12: aggregate: nodef + per-wave LN partials ============
  float ndf[2];
  {
    #pragma unroll
    for (int it = 0; it < 2; ++it) {
      int idx = it * 512 + tid;
      int ni = idx >> 8, c = idx & 255, h = c >> 5;
      float no = 0.f;
      #pragma unroll
      for (int k = 0; k < 32; ++k)
        no = fmaf(FSA(ni * 256 + k * 8 + h), b2f(smem[(ni * 32 + k) * BIGLD + c]), no);
      float nodef = no + p.nf[(size_t)(n0 + ni) * HH + c];
      ndf[it] = nodef;
      FSNF(idx) = nodef;
      float s = nodef, ss = nodef * nodef;
      #pragma unroll
      for (int m = 1; m < 64; m <<= 1) { s += __shfl_xor(s, m); ss += __shfl_xor(ss, m); }
      if (l == 0) { FLNP(it * 8 + w) = s; FLNP(16 + it * 8 + w) = ss; }
    }
  }
  __syncthreads();
  // ============ P13: LN2n -> NSTG rows 17..20 ; zero rows 21..32 ============
  {
    #pragma unroll
    for (int it = 0; it < 2; ++it) {
      int idx = it * 512 + tid;
      int ni = idx >> 8, c = idx & 255;
      int base = it * 8 + (ni & 1) * 4;
      float S  = FLNP(base) + FLNP(base + 1) + FLNP(base + 2) + FLNP(base + 3);
      float SS = FLNP(16 + base) + FLNP(16 + base + 1) + FLNP(16 + base + 2) + FLNP(16 + base + 3);
      float mean = S * (1.f / HH), var = SS * (1.f / HH) - mean * mean;
      float rstd = rsqrtf(var + 1e-5f);
      smem[(17 + ni) * BIGLD + 256 + c] = f2b((ndf[it] - mean) * rstd * p.ln2n_g[c] + p.ln2n_b[c]);
    }
    #pragma unroll
    for (int z = 0; z < 3; ++z) {
      int zi = z * 512 + tid;
      int zr = 21 + (zi >> 7), zc = (zi & 127) << 1;
      *(unsigned int*)(smem + zr * BIGLD + 256 + zc) = 0u;
    }
  }
  __syncthreads();
  // ============ P14: node FFN1 (reads rows 17..32, stores rows 33..64: no inner barrier) ============
  {
    f4 acc[4];
    #pragma unroll
    for (int ct = 0; ct < 4; ++ct) { acc[ct][0]=0.f; acc[ct][1]=0.f; acc[ct][2]=0.f; acc[ct][3]=0.f; }
    #pragma unroll
    for (int kb = 0; kb < 8; ++kb) {
      bs8 afr = *(const bs8*)(smem + (17 + lm) * BIGLD + 256 + kb * 32 + lg);
      #pragma unroll
      for (int ct = 0; ct < 4; ++ct) {
        bs8 wfr = *(const bs8*)(p.wtN1 + (size_t)(w * 64 + ct * 16 + lm) * 256 + kb * 32 + lg);
        acc[ct] = __builtin_amdgcn_mfma_f32_16x16x32_bf16(wfr, afr, acc[ct], 0, 0, 0);
      }
    }
    #pragma unroll
    for (int ct = 0; ct < 4; ++ct) {
      int col = w * 64 + ct * 16 + lr;
      f4 bv = *(const f4*)(p.bn1 + col);
      *(bs4*)(smem + (33 + 2 * lm + (col >= 256 ? 1 : 0)) * BIGLD + 256 + (col & 255)) =
          pack4(gelu_f(acc[ct][0] + bv[0]), gelu_f(acc[ct][1] + bv[1]),
                gelu_f(acc[ct][2] + bv[2]), gelu_f(acc[ct][3] + bv[3]));
    }
  }
  __syncthreads();
  // ============ P15: node FFN2 + residual -> on ; pack edge_f regs ============
  bs4 efp[8][2];
  {
    f4 acc[2];
    #pragma unroll
    for (int ct = 0; ct < 2; ++ct) { acc[ct][0]=0.f; acc[ct][1]=0.f; acc[ct][2]=0.f; acc[ct][3]=0.f; }
    #pragma unroll
    for (int kb = 0; kb < 16; ++kb) {
      bs8 afr = *(const bs8*)(smem + (33 + 2 * lm + (kb >> 3)) * BIGLD + 256 + (kb & 7) * 32 + lg);
      #pragma unroll
      for (int ct = 0; ct < 2; ++ct) {
        bs8 wfr = *(const bs8*)(p.wtN2 + (size_t)(w * 32 + ct * 16 + lm) * 512 + kb * 32 + lg);
        acc[ct] = __builtin_amdgcn_mfma_f32_16x16x32_bf16(wfr, afr, acc[ct], 0, 0, 0);
      }
    }
    if (lm < 4) {
      #pragma unroll
      for (int ct = 0; ct < 2; ++ct) {
        int col = w * 32 + ct * 16 + lr;
        f4 bv = *(const f4*)(p.bn2 + col);
        float4 o;
        o.x = acc[ct][0] + bv[0] + FSNF(lm * 256 + col);
        o.y = acc[ct][1] + bv[1] + FSNF(lm * 256 + col + 1);
        o.z = acc[ct][2] + bv[2] + FSNF(lm * 256 + col + 2);
        o.w = acc[ct][3] + bv[3] + FSNF(lm * 256 + col + 3);
        *(float4*)(p.on + (size_t)(n0 + lm) * HH + col) = o;
      }
    }
    #pragma unroll
    for (int rt = 0; rt < 8; ++rt)
      #pragma unroll
      for (int ct = 0; ct < 2; ++ct) {
        int row = rt * 16 + lm, col = w * 32 + ct * 16 + lr;
        bs4 ov = *(const bs4*)(smem + row * BIGLD + col);
        float4 e = *(const float4*)(p.ef + (ebase + row) * HH + col);
        efp[rt][ct] = pack4(e.x + b2f((unsigned short)ov[0]), e.y + b2f((unsigned short)ov[1]),
                            e.z + b2f((unsigned short)ov[2]), e.w + b2f((unsigned short)ov[3]));
      }
  }
  __syncthreads();
  // ============ P16: LN2e(eo + ef) -> cols 0:256 (overwrite eo) ============
  {
    int row = tid >> 2, q = tid & 3;
    const float* efs = p.ef + (ebase + row) * HH + q * 64;
    const unsigned short* eor = smem + row * BIGLD + q * 64;
    float xv[64];
    float s = 0.f, ss = 0.f;
    #pragma unroll
    for (int j = 0; j < 16; ++j) {
      float4 e = ((const float4*)efs)[j];
      bs4 ov = *(const bs4*)(eor + j * 4);
      float x0 = e.x + b2f((unsigned short)ov[0]);
      float x1 = e.y + b2f((unsigned short)ov[1]);
      float x2 = e.z + b2f((unsigned short)ov[2]);
      float x3 = e.w + b2f((unsigned short)ov[3]);
      xv[j * 4] = x0; xv[j * 4 + 1] = x1; xv[j * 4 + 2] = x2; xv[j * 4 + 3] = x3;
      s += x0 + x1 + x2 + x3;
      ss += x0 * x0 + x1 * x1 + x2 * x2 + x3 * x3;
    }
    s += __shfl_xor(s, 1); ss += __shfl_xor(ss, 1);
    s += __shfl_xor(s, 2); ss += __shfl_xor(ss, 2);
    float mean = s * (1.f / HH);
    float var = ss * (1.f / HH) - mean * mean;
    float rstd = rsqrtf(var + 1e-5f);
    unsigned short* d = smem + row * BIGLD + q * 64;
    #pragma unroll
    for (int j = 0; j < 16; ++j) {
      int c = q * 64 + j * 4;
      float4 g = *(const float4*)(p.ln2e_g + c);
      float4 b = *(const float4*)(p.ln2e_b + c);
      *(bs4*)(d + j * 4) = pack4((xv[j * 4] - mean) * rstd * g.x + b.x,
                                 (xv[j * 4 + 1] - mean) * rstd * g.y + b.y,
                                 (xv[j * 4 + 2] - mean) * rstd * g.z + b.z,
                                 (xv[j * 4 + 3] - mean) * rstd * g.w + b.w);
    }
  }
  __syncthreads();
  // ============ P17: E1 half0 (reads 0:256, stores 256:512: no inner barrier) ============
  f4 oacc[8][2]; zero_acc<8,2>(oacc);
  {
    f4 h[8][2]; zero_acc<8,2>(h);
    gemmB<8,2,8,256>(h, p.wtE1, smem, w * 32, l);
    storeB<8,2,1>(smem + 256, h, p.be1, w * 32, l);
  }
  __syncthreads();
  // ============ P18: E2 part0 + E1 half1 ; inner barrier ; E1b store ============
  {
    gemmB<8,2,8,512>(oacc, p.wtE2, smem + 256, w * 32, l);
    f4 h[8][2]; zero_acc<8,2>(h);
    gemmB<8,2,8,256>(h, p.wtE1 + (size_t)256 * 256, smem, w * 32, l);
    __syncthreads();
    storeB<8,2,1>(smem + 256, h, p.be1 + 256, w * 32, l);
  }
  __syncthreads();
  // ============ P19: E2 part1 + epilogue -> oe ============
  {
    gemmB<8,2,8,512>(oacc, p.wtE2 + 256, smem + 256, w * 32, l);
    #pragma unroll
    for (int ct = 0; ct < 2; ++ct) {
      f4 bv = *(const f4*)(p.be2 + w * 32 + ct * 16 + lr);
      #pragma unroll
      for (int rt = 0; rt < 8; ++rt) {
        int row = rt * 16 + lm;
        float4 o;
        o.x = oacc[rt][ct][0] + bv[0] + b2f((unsigned short)efp[rt][ct][0]);
        o.y = oacc[rt][ct][1] + bv[1] + b2f((unsigned short)efp[rt][ct][1]);
        o.z = oacc[rt][ct][2] + bv[2] + b2f((unsigned short)efp[rt][ct][2]);
        o.w = oacc[rt][ct][3] + bv[3] + b2f((unsigned short)efp[rt][ct][3]);
        *(float4*)(p.oe + (ebase + row) * HH + w * 32 + ct * 16 + lr) = o;
      }
    }
  }
  #undef FSA
  #undef FSNF
  #undef FLNP
}

extern "C" void kernel_launch(void* const* d_in, const int* in_sizes, int n_in,
                              void* d_out, int out_size, void* d_ws, size_t ws_size,
                              hipStream_t stream)
{
  P p;
  p.nf     = (const float*)d_in[0];
  p.ef     = (const float*)d_in[1];
  p.ear    = (const float*)d_in[2];
  p.ang    = (const float*)d_in[3];
  const float* ln1n_g = (const float*)d_in[4];
  const float* ln1n_b = (const float*)d_in[5];
  p.ln1e_g = (const float*)d_in[6];  p.ln1e_b = (const float*)d_in[7];
  const float* W_ea   = (const float*)d_in[8];  p.b_ea   = (const float*)d_in[9];
  const float* W_nh   = (const float*)d_in[10]; p.b_nh   = (const float*)d_in[11];
  const float* W_eh   = (const float*)d_in[12]; p.b_eh   = (const float*)d_in[13];
  const float* W_gate = (const float*)d_in[14]; p.b_gate = (const float*)d_in[15];
  const float* W_cand = (const float*)d_in[16]; p.b_cand = (const float*)d_in[17];
  p.ascal  = (const float*)d_in[18];
  const float* W_in   = (const float*)d_in[19]; p.b_in   = (const float*)d_in[20];
  const float* W_out  = (const float*)d_in[21]; p.b_out  = (const float*)d_in[22];
  p.aw     = (const float*)d_in[23];
  p.ln2n_g = (const float*)d_in[24]; p.ln2n_b = (const float*)d_in[25];
  p.ln2e_g = (const float*)d_in[26]; p.ln2e_b = (const float*)d_in[27];
  const float* Wn1 = (const float*)d_in[28]; p.bn1 = (const float*)d_in[29];
  const float* Wn2 = (const float*)d_in[30]; p.bn2 = (const float*)d_in[31];
  const float* We1 = (const float*)d_in[32]; p.be1 = (const float*)d_in[33];
  const float* We2 = (const float*)d_in[34]; p.be2 = (const float*)d_in[35];
  p.nbrl   = (const int*)d_in[36];
  p.nbrc   = (const int*)d_in[37];
  p.on     = (float*)d_out;
  p.oe     = (float*)d_out + (size_t)NN * HH;

  size_t off = 0;
  auto alloc = [&](size_t elems) {
    unsigned short* q = (unsigned short*)((char*)d_ws + off);
    off += elems * 2;
    return q;
  };
  unsigned short* nhb = alloc((size_t)NN * HH);
  unsigned short* wtEA  = alloc(256 * 128);
  unsigned short* wtNH  = alloc(256 * 256);
  unsigned short* wtEH  = alloc(256 * 256);
  unsigned short* wtG   = alloc(256 * 512);
  unsigned short* wtC   = alloc(256 * 512);
  unsigned short* wtIN  = alloc(768 * 256);
  unsigned short* wtOUT = alloc(256 * 256);
  unsigned short* wtN1  = alloc(512 * 256);
  unsigned short* wtN2  = alloc(256 * 512);
  unsigned short* wtE1  = alloc(512 * 256);
  unsigned short* wtE2  = alloc(256 * 512);
  p.nhb = nhb;
  p.wtEA = wtEA; p.wtNH = wtNH; p.wtEH = wtEH; p.wtG = wtG; p.wtC = wtC;
  p.wtIN = wtIN; p.wtOUT = wtOUT; p.wtN1 = wtN1; p.wtN2 = wtN2; p.wtE1 = wtE1; p.wtE2 = wtE2;

  node_ln_bf16<<<NN / 4, 256, 0, stream>>>((const float*)d_in[0], ln1n_g, ln1n_b, nhb);

  auto tr = [&](const float* src, unsigned short* dst, int K, int C) {
    wt_transpose<<<dim3(K / 32, C / 32), 256, 0, stream>>>(src, dst, K, C);
  };
  tr(W_ea, wtEA, 128, 256);
  tr(W_nh, wtNH, 256, 256);
  tr(W_eh, wtEH, 256, 256);
  tr(W_gate, wtG, 512, 256);
  tr(W_cand, wtC, 512, 256);
  tr(W_in, wtIN, 256, 768);
  tr(W_out, wtOUT, 256, 256);
  tr(Wn1, wtN1, 256, 512);
  tr(Wn2, wtN2, 512, 256);
  tr(We1, wtE1, 256, 512);
  tr(We2, wtE2, 512, 256);

  (void)hipFuncSetAttribute((const void*)mega_kernel,
                            hipFuncAttributeMaxDynamicSharedMemorySize, LDS_BYTES);
  mega_kernel<<<NN / NODES, THREADS, LDS_BYTES, stream>>>(p);
}